// Round 17
// baseline (295.953 us; speedup 1.0000x reference)
//
#include <hip/hip_runtime.h>
#include <math.h>

#define ATT_SCALE 0.17677669529663687f  // 32^-0.5

typedef __bf16 bf16x8 __attribute__((ext_vector_type(8)));
typedef __bf16 bf16x4 __attribute__((ext_vector_type(4)));
typedef float  f32x4  __attribute__((ext_vector_type(4)));

#define MFMA16(a,b,c) __builtin_amdgcn_mfma_f32_16x16x32_bf16(a,b,c,0,0,0)

// ws layout: [0,786432) f32 expanded bias; then bf16 swizzled weights; then optional bf16 attn-out
#define BIAS_BYTES 786432
#define WKV_OFF 0        // 192x384  kt6  NRT24
#define WQ_OFF  73728    // 96x192   kt3  NRT12 (pre-scaled)   [contiguous with WP]
#define WP_OFF  92160    // 192x96   kt6  NRT6
#define WD_OFF  110592   // deconv: [ii2][kt6][rt24][lane][8], rows m = (2j+k)*96+o
#define W1_OFF  258048   // 96x384   kt3  NRT24
#define W2_OFF  294912   // 384x96   kt12 NRT6
#define NSWZ    331776
#define AOUT_OFF 1507328ull                       // byte offset of bf16 attn-out in ws
#define AOUT_BYTES (262144ull * 96ull * 2ull)     // 50331648

static __device__ __forceinline__ float gelu_exact(float v){
    return 0.5f * v * (1.0f + erff(v * 0.70710678118654752f));
}

static __device__ __forceinline__ bf16x8 afrag(const __bf16* w, int NRT, int kt, int rt, int lane){
    return ((const bf16x8*)w)[(kt*NRT + rt)*64 + lane];
}

// ---------------- prep: bias expand + weight bf16 swizzle (proven r8-r16) ----------------
__global__ __launch_bounds__(256) void k_prep(const float* __restrict__ table,
    const float* __restrict__ Wkv, const float* __restrict__ Wq,
    const float* __restrict__ Wp,  const float* __restrict__ Wd,
    const float* __restrict__ W1,  const float* __restrict__ W2,
    float* __restrict__ bias, __bf16* __restrict__ wsw){
    int id = blockIdx.x * 256 + threadIdx.x;
    if (id < 196608){
        int k  = id & 63;
        int qg = (id >> 6) & 511;
        int h  = id >> 15;
        int qi = qg >> 6, qj = (qg >> 3) & 7, qk = qg & 7;
        int ki = k >> 4,  kj = (k >> 2) & 3,  kk = k & 3;
        int r0 = (qi >> 1) - ki + 3;
        int r1 = (qj >> 1) - kj + 3;
        int r2 = (qk >> 1) - kk + 3;
        bias[id] = table[((r0 * 7 + r1) * 7 + r2) * 6 + h];
        return;
    }
    id -= 196608;
    if (id >= NSWZ) return;
    if (id >= WD_OFF && id < W1_OFF){
        int lid  = id - WD_OFF;
        int j    = lid & 7, lane = (lid >> 3) & 63, tile = lid >> 9;
        int rt   = tile % 24;
        int kt2  = tile / 24;
        int ii   = kt2 / 6, kt = kt2 % 6;
        int n    = rt * 16 + (lane & 15);
        int o    = n % 96, jk = n / 96;
        int kdim = kt * 32 + (lane >> 4) * 8 + j;
        wsw[id] = (__bf16)(Wd[(kdim * 96 + o) * 8 + ii * 4 + jk]);
        return;
    }
    const float* W; int N, NRT, off; float sc = 1.f;
    if      (id < WQ_OFF){ W = Wkv; N = 384; NRT = 24; off = WKV_OFF; }
    else if (id < WP_OFF){ W = Wq;  N = 192; NRT = 12; off = WQ_OFF; sc = ATT_SCALE; }
    else if (id < WD_OFF){ W = Wp;  N = 96;  NRT = 6;  off = WP_OFF; }
    else if (id < W2_OFF){ W = W1;  N = 384; NRT = 24; off = W1_OFF; }
    else                 { W = W2;  N = 96;  NRT = 6;  off = W2_OFF; }
    int lid  = id - off;
    int j    = lid & 7, lane = (lid >> 3) & 63, tile = lid >> 9;
    int rt   = tile % NRT, kt = tile / NRT;
    int n    = rt * 16 + (lane & 15);
    int k    = kt * 32 + (lane >> 4) * 8 + j;
    wsw[id + 0] = (__bf16)(W[k * N + n] * sc);
}

// ---------------- fused windowed cross-attention (MFMA): attn + bpj (PURE STORE) ----------------
// r16-proven; dual-path store: bf16 to aout (ws) when available, else f32 to d_out.
__global__ __launch_bounds__(512) void k_attn(const float* __restrict__ x,
    const float* __restrict__ xd, const float* __restrict__ g1, const float* __restrict__ b1v,
    const float* __restrict__ bkv, const float* __restrict__ bq, const float* __restrict__ bpj,
    const __bf16* __restrict__ wsw, const float* __restrict__ bias, float* __restrict__ yout,
    __bf16* __restrict__ aout){
    __shared__ __bf16 Qs[64][196];   // xln -> Q -> attn-out (aliased phases)
    __shared__ __bf16 Ks[64][196];
    __shared__ __bf16 Vt[192][68];   // V transposed [d][kv]
    __shared__ __bf16 Wqp_s[36864];  // WQ (18432) ++ WP (18432), 72 KB, used 8x each
    const int tid = threadIdx.x, lane = tid & 63, w = tid >> 6;
    const int win = blockIdx.x, b = win >> 8, wrem = win & 255;
    const int sw_ = wrem >> 6, hw_ = (wrem >> 3) & 7, ww_ = wrem & 7;

    // stage WQ+WP (contiguous in ws) into LDS; covered by the first barrier
    #pragma unroll
    for (int i = 0; i < 9; i++)
        ((uint4*)Wqp_s)[tid + 512*i] = ((const uint4*)(wsw + WQ_OFF))[tid + 512*i];

    {   // LN stage of coarse x window -> Qs (as xln)
        int row = tid >> 3, sub = tid & 7;
        int si = row >> 4, hi = (row >> 2) & 3, wi = row & 3;
        int ci = ((b * 16 + 4 * sw_ + si) * 32 + 4 * hw_ + hi) * 32 + 4 * ww_ + wi;
        const float* xp = x + ci * 192 + sub * 24;
        float v[24]; float s = 0.f, ss = 0.f;
        #pragma unroll
        for (int i = 0; i < 6; i++){
            float4 t = ((const float4*)xp)[i];
            v[4*i] = t.x; v[4*i+1] = t.y; v[4*i+2] = t.z; v[4*i+3] = t.w;
            s += t.x + t.y + t.z + t.w;
            ss += t.x*t.x + t.y*t.y + t.z*t.z + t.w*t.w;
        }
        #pragma unroll
        for (int m = 1; m < 8; m <<= 1){ s += __shfl_xor(s, m); ss += __shfl_xor(ss, m); }
        float mu = s * (1.f/192.f), var = ss * (1.f/192.f) - mu*mu, rs = rsqrtf(var + 1e-5f);
        #pragma unroll
        for (int i = 0; i < 3; i++){
            bf16x8 t;
            #pragma unroll
            for (int jj = 0; jj < 8; jj++){
                int c = sub*24 + 8*i + jj;
                t[jj] = (__bf16)((v[8*i+jj] - mu) * rs * g1[c] + b1v[c]);
            }
            *(bf16x8*)&Qs[row][sub*24 + 8*i] = t;
        }
    }
    __syncthreads();
    {   // KVproj: KV^T = Wkv^T @ xln^T ; waves 0-3 -> K rows, 4-7 -> V^T
        const int ct = w & 3, rh = w >> 2;
        const int tok = ct * 16 + (lane & 15);
        bf16x8 bfr[6];
        #pragma unroll
        for (int kt = 0; kt < 6; kt++) bfr[kt] = *(const bf16x8*)&Qs[tok][kt*32 + (lane>>4)*8];
        #pragma unroll
        for (int i = 0; i < 12; i++){
            int rt = rh * 12 + i;
            f32x4 acc = {0.f,0.f,0.f,0.f};
            #pragma unroll
            for (int kt = 0; kt < 6; kt++) acc = MFMA16(afrag(wsw + WKV_OFF, 24, kt, rt, lane), bfr[kt], acc);
            int cb = rt * 16 + ((lane >> 4) << 2);
            float4 b4 = *(const float4*)&bkv[cb];
            acc[0] += b4.x; acc[1] += b4.y; acc[2] += b4.z; acc[3] += b4.w;
            if (cb < 192){
                bf16x4 t;
                #pragma unroll
                for (int r = 0; r < 4; r++) t[r] = (__bf16)acc[r];
                *(bf16x4*)&Ks[tok][cb] = t;
            } else {
                #pragma unroll
                for (int r = 0; r < 4; r++) Vt[cb - 192 + r][tok] = (__bf16)acc[r];
            }
        }
    }
    __syncthreads();

    const int li_ = lane & 15, gt_ = lane >> 4, rsel = lane >> 5;

    for (int qt = 0; qt < 8; qt++){
        {   // Qproj: Q^T = Wq^T(scaled) @ xd^T ; A-frags from LDS, B-frags from global f32
            const int ct = w & 3, rh = w >> 2;
            const int ql = ct * 16 + (lane & 15);
            const int ft = ((b * 32 + 8 * sw_ + qt) * 64 + 8 * hw_ + (ql >> 3)) * 64 + 8 * ww_ + (ql & 7);
            bf16x8 bfr[3];
            #pragma unroll
            for (int kt = 0; kt < 3; kt++){
                const float* xp = xd + ft * 96 + kt * 32 + (lane >> 4) * 8;
                float4 t0 = *(const float4*)xp;
                float4 t1 = *(const float4*)(xp + 4);
                bf16x8 t;
                t[0]=(__bf16)t0.x; t[1]=(__bf16)t0.y; t[2]=(__bf16)t0.z; t[3]=(__bf16)t0.w;
                t[4]=(__bf16)t1.x; t[5]=(__bf16)t1.y; t[6]=(__bf16)t1.z; t[7]=(__bf16)t1.w;
                bfr[kt] = t;
            }
            #pragma unroll
            for (int i = 0; i < 6; i++){
                int rt = rh * 6 + i;
                f32x4 acc = {0.f,0.f,0.f,0.f};
                #pragma unroll
                for (int kt = 0; kt < 3; kt++) acc = MFMA16(afrag(Wqp_s, 12, kt, rt, lane), bfr[kt], acc);
                int cb = rt * 16 + ((lane >> 4) << 2);
                float4 b4 = *(const float4*)&bq[cb];
                bf16x4 t;
                t[0] = (__bf16)(acc[0] + b4.x * ATT_SCALE);
                t[1] = (__bf16)(acc[1] + b4.y * ATT_SCALE);
                t[2] = (__bf16)(acc[2] + b4.z * ATT_SCALE);
                t[3] = (__bf16)(acc[3] + b4.w * ATT_SCALE);
                *(bf16x4*)&Qs[ql][cb] = t;
            }
        }
        __syncthreads();
        // scores + softmax + in-register P redistribution + PV
        f32x4 ov[3][2];
        #pragma unroll
        for (int ui = 0; ui < 3; ui++){
            const int u = w * 3 + ui;
            const int h = u >> 2, qct = u & 3;
            f32x4 sc[4];
            __builtin_amdgcn_s_setprio(1);
            #pragma unroll
            for (int rt = 0; rt < 4; rt++){
                bf16x8 a  = *(const bf16x8*)&Ks[rt*16 + li_][h*32 + gt_*8];
                bf16x8 bq8 = *(const bf16x8*)&Qs[qct*16 + li_][h*32 + gt_*8];
                f32x4 z = {0.f,0.f,0.f,0.f};
                sc[rt] = MFMA16(a, bq8, z);
            }
            __builtin_amdgcn_s_setprio(0);
            const int qg = qt * 64 + qct * 16 + li_;
            const float* bp = bias + (h * 512 + qg) * 64 + (gt_ << 2);
            #pragma unroll
            for (int rt = 0; rt < 4; rt++){
                float4 b4 = *(const float4*)(bp + rt * 16);
                sc[rt][0] += b4.x; sc[rt][1] += b4.y; sc[rt][2] += b4.z; sc[rt][3] += b4.w;
            }
            float m = sc[0][0];
            #pragma unroll
            for (int rt = 0; rt < 4; rt++)
                #pragma unroll
                for (int r = 0; r < 4; r++) m = fmaxf(m, sc[rt][r]);
            m = fmaxf(m, __shfl_xor(m, 16));
            m = fmaxf(m, __shfl_xor(m, 32));
            float sum = 0.f;
            #pragma unroll
            for (int rt = 0; rt < 4; rt++)
                #pragma unroll
                for (int r = 0; r < 4; r++){ float e = __expf(sc[rt][r] - m); sc[rt][r] = e; sum += e; }
            sum += __shfl_xor(sum, 16);
            sum += __shfl_xor(sum, 32);
            float inv = 1.f / sum;
            // pack normalized P into bf16 pair words: pwv[rt][h2] covers kv = rt*16+gt*4+2*h2+{0,1}
            unsigned pwv[4][2];
            #pragma unroll
            for (int rt = 0; rt < 4; rt++){
                union { __bf16 hh[2]; unsigned u; } c0, c1;
                c0.hh[0] = (__bf16)(sc[rt][0] * inv); c0.hh[1] = (__bf16)(sc[rt][1] * inv);
                c1.hh[0] = (__bf16)(sc[rt][2] * inv); c1.hh[1] = (__bf16)(sc[rt][3] * inv);
                pwv[rt][0] = c0.u; pwv[rt][1] = c1.u;
            }
            // redistribute C-frag -> B-frag layout
            unsigned bfw[2][4];
            #pragma unroll
            for (int kt = 0; kt < 2; kt++){
                #pragma unroll
                for (int t = 0; t < 4; t++){
                    int gs   = ((gt_ & 1) << 1) + (t >> 1);
                    int addr = (((gs << 4) + li_) << 2);
                    int w0 = __builtin_amdgcn_ds_bpermute(addr, (int)pwv[2*kt + 0][t & 1]);
                    int w1 = __builtin_amdgcn_ds_bpermute(addr, (int)pwv[2*kt + 1][t & 1]);
                    bfw[kt][t] = rsel ? (unsigned)w1 : (unsigned)w0;
                }
            }
            union { unsigned u[4]; bf16x8 v; } pb0, pb1;
            #pragma unroll
            for (int t = 0; t < 4; t++){ pb0.u[t] = bfw[0][t]; pb1.u[t] = bfw[1][t]; }
            __builtin_amdgcn_s_setprio(1);
            #pragma unroll
            for (int dt = 0; dt < 2; dt++){
                f32x4 o = {0.f,0.f,0.f,0.f};
                bf16x8 a0 = *(const bf16x8*)&Vt[h*32 + dt*16 + li_][gt_*8];
                bf16x8 a1 = *(const bf16x8*)&Vt[h*32 + dt*16 + li_][32 + gt_*8];
                o = MFMA16(a0, pb0.v, o);
                o = MFMA16(a1, pb1.v, o);
                ov[ui][dt] = o;
            }
            __builtin_amdgcn_s_setprio(0);
        }
        __syncthreads();   // all Qs reads done
        #pragma unroll
        for (int ui = 0; ui < 3; ui++){
            const int u = w * 3 + ui;
            const int h = u >> 2, qct = u & 3;
            const int tok = qct * 16 + li_;
            #pragma unroll
            for (int dt = 0; dt < 2; dt++){
                int cb = h * 32 + dt * 16 + (gt_ << 2);
                bf16x4 t;
                #pragma unroll
                for (int r = 0; r < 4; r++) t[r] = (__bf16)ov[ui][dt][r];
                *(bf16x4*)&Qs[tok][cb] = t;
            }
        }
        __syncthreads();
        {   // outproj: Y^T = Wp^T @ out^T + bpj ; store bf16->aout or f32->d_out
            const int ct = w & 3, rh = w >> 2;
            const int ql = ct * 16 + (lane & 15);
            const int ft = ((b * 32 + 8 * sw_ + qt) * 64 + 8 * hw_ + (ql >> 3)) * 64 + 8 * ww_ + (ql & 7);
            bf16x8 bfr[6];
            #pragma unroll
            for (int kt = 0; kt < 6; kt++) bfr[kt] = *(const bf16x8*)&Qs[ql][kt*32 + (lane>>4)*8];
            #pragma unroll
            for (int i = 0; i < 3; i++){
                int rt = rh * 3 + i;
                f32x4 acc = {0.f,0.f,0.f,0.f};
                #pragma unroll
                for (int kt = 0; kt < 6; kt++) acc = MFMA16(afrag(Wqp_s + 18432, 6, kt, rt, lane), bfr[kt], acc);
                int cb = rt * 16 + ((lane >> 4) << 2);
                float4 b4 = *(const float4*)&bpj[cb];
                float4 res;
                res.x = acc[0] + b4.x;
                res.y = acc[1] + b4.y;
                res.z = acc[2] + b4.z;
                res.w = acc[3] + b4.w;
                if (aout){
                    bf16x4 tb;
                    tb[0] = (__bf16)res.x; tb[1] = (__bf16)res.y;
                    tb[2] = (__bf16)res.z; tb[3] = (__bf16)res.w;
                    *(bf16x4*)&aout[ft * 96 + cb] = tb;
                } else {
                    *(float4*)&yout[ft * 96 + cb] = res;
                }
            }
        }
        __syncthreads();   // before next qt overwrites Qs
    }
}

// ---------------- MLP + fused deconv: xe/hsm LDS union -> 38.5 KB -> 4 blocks/CU ----------------
__global__ __launch_bounds__(512) void k_mlp(const float* __restrict__ x,
    const float* __restrict__ eg, const float* __restrict__ eb,
    const float* __restrict__ g2, const float* __restrict__ b2v,
    const __bf16* __restrict__ wsw, const float* __restrict__ db,
    const float* __restrict__ b1m, const float* __restrict__ b2m,
    float* __restrict__ outp, const __bf16* __restrict__ ain){
    __shared__ __bf16 pool[6656];     // xe[32][200] (phases 1-2) then hsm[64][104] (phases 4+), 13.0 KB
    __shared__ __bf16 ybf[64][100];   // sc then y, bf16 (12.5 KB)
    __shared__ __bf16 yln[64][104];   // LN(y) (13.0 KB)
    __bf16 (* const xe)[200]  = (__bf16(*)[200])pool;
    __bf16 (* const hsm)[104] = (__bf16(*)[104])pool;
    const int tid = threadIdx.x, lane = tid & 63, w = tid >> 6;
    const int t0 = blockIdx.x * 64;
    const int bb   = t0 >> 17;
    const int sbar = (t0 >> 12) & 31;
    const int hbar = (t0 >> 6) & 63;
    const int iD = sbar & 1, jD = hbar & 1;
    const int sc_ = sbar >> 1, hc_ = hbar >> 1;

    // T14 prefetch: this thread's attn values — consumed 2 phases later
    float4 apf[3];
    {
        int rowP = tid >> 3, subP = tid & 7;
        if (ain){
            const __bf16* ap = ain + (t0 + rowP) * 96 + subP * 12;
            #pragma unroll
            for (int i2 = 0; i2 < 3; i2++){
                bf16x4 a4 = ((const bf16x4*)ap)[i2];
                apf[i2].x = (float)a4[0]; apf[i2].y = (float)a4[1];
                apf[i2].z = (float)a4[2]; apf[i2].w = (float)a4[3];
            }
        } else {
            const float* ap = outp + (t0 + rowP) * 96 + subP * 12;
            apf[0] = ((const float4*)ap)[0];
            apf[1] = ((const float4*)ap)[1];
            apf[2] = ((const float4*)ap)[2];
        }
    }

    {   // stage 32 coarse x rows + expand-LN -> xe  (16 threads/row, 12 ch each)
        int row = tid >> 4, sub = tid & 15;
        int ci = ((bb * 16 + sc_) * 32 + hc_) * 32 + row;
        const float* xp = x + ci * 192 + sub * 12;
        float v[12]; float s = 0.f, ss = 0.f;
        #pragma unroll
        for (int i2 = 0; i2 < 3; i2++){
            float4 t = ((const float4*)xp)[i2];
            v[4*i2] = t.x; v[4*i2+1] = t.y; v[4*i2+2] = t.z; v[4*i2+3] = t.w;
            s += t.x + t.y + t.z + t.w;
            ss += t.x*t.x + t.y*t.y + t.z*t.z + t.w*t.w;
        }
        #pragma unroll
        for (int m = 1; m < 16; m <<= 1){ s += __shfl_xor(s, m); ss += __shfl_xor(ss, m); }
        float mu = s * (1.f/192.f), var = ss * (1.f/192.f) - mu*mu, rs = rsqrtf(var + 1e-5f);
        #pragma unroll
        for (int i2 = 0; i2 < 3; i2++){
            bf16x4 t;
            #pragma unroll
            for (int jj = 0; jj < 4; jj++){
                int c = sub*12 + 4*i2 + jj;
                t[jj] = (__bf16)((v[4*i2+jj] - mu) * rs * eg[c] + eb[c]);
            }
            *(bf16x4*)&xe[row][sub*12 + 4*i2] = t;
        }
    }
    __syncthreads();
    {   // deconv slice GEMM: C'[k*96+o][w] over K=192 -> ybf[2w+k][o] = sc + db (bf16)
        const int li = lane & 15, gt = lane >> 4;
        const int ctD = w & 1, rhD = w >> 1;
        const int wcol = ctD * 16 + li;
        bf16x8 bfrD[6];
        #pragma unroll
        for (int kt = 0; kt < 6; kt++) bfrD[kt] = *(const bf16x8*)&xe[wcol][kt*32 + gt*8];
        const __bf16* wd = wsw + WD_OFF + iD * 73728;
        #pragma unroll
        for (int i2 = 0; i2 < 3; i2++){
            int rtl = rhD * 3 + i2;               // [0,12)
            int rt  = 12 * jD + rtl;              // row tile in the ii=iD bank
            f32x4 acc = {0.f,0.f,0.f,0.f};
            #pragma unroll
            for (int kt = 0; kt < 6; kt++) acc = MFMA16(afrag(wd, 24, kt, rt, lane), bfrD[kt], acc);
            int mp   = rtl * 16 + (gt << 2);      // m' = k*96+o
            int kpar = (mp >= 96) ? 1 : 0;
            int o    = mp - 96 * kpar;
            int tok  = 2 * wcol + kpar;
            float4 d4 = *(const float4*)&db[o];
            bf16x4 t;
            t[0] = (__bf16)(acc[0] + d4.x); t[1] = (__bf16)(acc[1] + d4.y);
            t[2] = (__bf16)(acc[2] + d4.z); t[3] = (__bf16)(acc[3] + d4.w);
            *(bf16x4*)&ybf[tok][o] = t;
        }
    }
    __syncthreads();
    {   // y = attn(prefetched) + sc ; write y -> ybf (bf16) ; LN -> yln
        int row = tid >> 3, sub = tid & 7;
        float v[12]; float s = 0.f, ss = 0.f;
        #pragma unroll
        for (int i2 = 0; i2 < 3; i2++){
            float4 t = apf[i2];
            bf16x4 s4 = *(const bf16x4*)&ybf[row][sub*12 + 4*i2];
            t.x += (float)s4[0]; t.y += (float)s4[1];
            t.z += (float)s4[2]; t.w += (float)s4[3];
            v[4*i2] = t.x; v[4*i2+1] = t.y; v[4*i2+2] = t.z; v[4*i2+3] = t.w;
            s += t.x + t.y + t.z + t.w;
            ss += t.x*t.x + t.y*t.y + t.z*t.z + t.w*t.w;
            bf16x4 yb;
            yb[0] = (__bf16)t.x; yb[1] = (__bf16)t.y;
            yb[2] = (__bf16)t.z; yb[3] = (__bf16)t.w;
            *(bf16x4*)&ybf[row][sub*12 + 4*i2] = yb;   // y residual (bf16)
        }
        #pragma unroll
        for (int m = 1; m < 8; m <<= 1){ s += __shfl_xor(s, m); ss += __shfl_xor(ss, m); }
        float mu = s * (1.f/96.f), var = ss * (1.f/96.f) - mu*mu, rs = rsqrtf(var + 1e-5f);
        #pragma unroll
        for (int i2 = 0; i2 < 3; i2++){
            bf16x4 t;
            #pragma unroll
            for (int jj = 0; jj < 4; jj++){
                int c = sub*12 + 4*i2 + jj;
                t[jj] = (__bf16)((v[4*i2+jj] - mu) * rs * g2[c] + b2v[c]);
            }
            *(bf16x4*)&yln[row][sub*12 + 4*i2] = t;
        }
    }
    __syncthreads();
    const int ct = w & 3, rh = w >> 2;
    const int tok = ct * 16 + (lane & 15);
    bf16x8 bfrY[3];
    #pragma unroll
    for (int kt = 0; kt < 3; kt++) bfrY[kt] = *(const bf16x8*)&yln[tok][kt*32 + (lane>>4)*8];
    f32x4 oacc[3];
    #pragma unroll
    for (int i = 0; i < 3; i++){ f32x4 z = {0.f,0.f,0.f,0.f}; oacc[i] = z; }

    #pragma unroll
    for (int ch = 0; ch < 4; ch++){
        // GEMM1 chunk: 96 hidden channels -> hsm (aliases dead xe)
        #pragma unroll
        for (int i = 0; i < 3; i++){
            int rtl = rh * 3 + i;            // [0,6)
            int rtg = ch * 6 + rtl;
            f32x4 acc = {0.f,0.f,0.f,0.f};
            #pragma unroll
            for (int kt = 0; kt < 3; kt++) acc = MFMA16(afrag(wsw + W1_OFF, 24, kt, rtg, lane), bfrY[kt], acc);
            int cb = rtl * 16 + ((lane >> 4) << 2);
            float4 b4 = *(const float4*)&b1m[ch * 96 + cb];
            bf16x4 t;
            t[0] = (__bf16)gelu_exact(acc[0] + b4.x);
            t[1] = (__bf16)gelu_exact(acc[1] + b4.y);
            t[2] = (__bf16)gelu_exact(acc[2] + b4.z);
            t[3] = (__bf16)gelu_exact(acc[3] + b4.w);
            *(bf16x4*)&hsm[tok][cb] = t;
        }
        __syncthreads();
        // GEMM2 chunk: accumulate o^T += W2chunk^T @ h^T
        bf16x8 bfrH[3];
        #pragma unroll
        for (int kt = 0; kt < 3; kt++) bfrH[kt] = *(const bf16x8*)&hsm[tok][kt*32 + (lane>>4)*8];
        #pragma unroll
        for (int i = 0; i < 3; i++){
            int rt = rh * 3 + i;
            #pragma unroll
            for (int kt = 0; kt < 3; kt++)
                oacc[i] = MFMA16(afrag(wsw + W2_OFF, 6, ch * 3 + kt, rt, lane), bfrH[kt], oacc[i]);
        }
        __syncthreads();
    }
    #pragma unroll
    for (int i = 0; i < 3; i++){
        int rt = rh * 3 + i;
        int cb = rt * 16 + ((lane >> 4) << 2);
        float4 b4 = *(const float4*)&b2m[cb];
        bf16x4 yv = *(const bf16x4*)&ybf[tok][cb];
        float4 res;
        res.x = (float)yv[0] + oacc[i][0] + b4.x;
        res.y = (float)yv[1] + oacc[i][1] + b4.y;
        res.z = (float)yv[2] + oacc[i][2] + b4.z;
        res.w = (float)yv[3] + oacc[i][3] + b4.w;
        *(float4*)&outp[(t0 + tok) * 96 + cb] = res;
    }
}

extern "C" void kernel_launch(void* const* d_in, const int* in_sizes, int n_in,
                              void* d_out, int out_size, void* d_ws, size_t ws_size,
                              hipStream_t stream){
    const float* x    = (const float*)d_in[0];
    const float* xd   = (const float*)d_in[1];
    const float* g1   = (const float*)d_in[2];
    const float* b1v  = (const float*)d_in[3];
    const float* Wkv  = (const float*)d_in[4];
    const float* bkv  = (const float*)d_in[5];
    const float* Wq   = (const float*)d_in[6];
    const float* bq   = (const float*)d_in[7];
    const float* Wp   = (const float*)d_in[8];
    const float* bpj  = (const float*)d_in[9];
    const float* btab = (const float*)d_in[10];
    const float* eg   = (const float*)d_in[11];
    const float* eb   = (const float*)d_in[12];
    const float* dw   = (const float*)d_in[13];
    const float* db   = (const float*)d_in[14];
    const float* g2   = (const float*)d_in[15];
    const float* b2v  = (const float*)d_in[16];
    const float* W1   = (const float*)d_in[17];
    const float* b1m  = (const float*)d_in[18];
    const float* W2   = (const float*)d_in[19];
    const float* b2m  = (const float*)d_in[20];
    (void)in_sizes; (void)n_in; (void)out_size;

    float*   out  = (float*)d_out;
    float*   bias = (float*)d_ws;
    __bf16*  wsw  = (__bf16*)((char*)d_ws + BIAS_BYTES);
    __bf16*  aout = (ws_size >= AOUT_OFF + AOUT_BYTES)
                    ? (__bf16*)((char*)d_ws + AOUT_OFF) : (__bf16*)nullptr;

    k_prep<<<2064, 256, 0, stream>>>(btab, Wkv, Wq, Wp, dw, W1, W2, bias, wsw);
    k_attn<<<512, 512, 0, stream>>>(x, xd, g1, b1v, bkv, bq, bpj, wsw, bias, out, aout);
    k_mlp <<<4096, 512, 0, stream>>>(x, eg, eb, g2, b2v, wsw, db, b1m, b2m, out, aout);
}

// Round 18
// 293.555 us; speedup vs baseline: 1.0082x; 1.0082x over previous
//
#include <hip/hip_runtime.h>
#include <math.h>

#define ATT_SCALE 0.17677669529663687f  // 32^-0.5

typedef __bf16 bf16x8 __attribute__((ext_vector_type(8)));
typedef __bf16 bf16x4 __attribute__((ext_vector_type(4)));
typedef float  f32x4  __attribute__((ext_vector_type(4)));

#define MFMA16(a,b,c) __builtin_amdgcn_mfma_f32_16x16x32_bf16(a,b,c,0,0,0)

// ws layout: [0,786432) f32 expanded bias; then bf16 swizzled weights; then optional bf16 attn-out
#define BIAS_BYTES 786432
#define WKV_OFF 0        // 192x384  kt6  NRT24
#define WQ_OFF  73728    // 96x192   kt3  NRT12 (pre-scaled)   [contiguous with WP]
#define WP_OFF  92160    // 192x96   kt6  NRT6
#define WD_OFF  110592   // deconv: [ii2][kt6][rt24][lane][8], rows m = (2j+k)*96+o
#define W1_OFF  258048   // 96x384   kt3  NRT24
#define W2_OFF  294912   // 384x96   kt12 NRT6
#define NSWZ    331776
#define AOUT_OFF 1507328ull                       // byte offset of bf16 attn-out in ws
#define AOUT_BYTES (262144ull * 96ull * 2ull)     // 50331648

static __device__ __forceinline__ float gelu_exact(float v){
    return 0.5f * v * (1.0f + erff(v * 0.70710678118654752f));
}

static __device__ __forceinline__ bf16x8 afrag(const __bf16* w, int NRT, int kt, int rt, int lane){
    return ((const bf16x8*)w)[(kt*NRT + rt)*64 + lane];
}

// ---------------- prep: bias expand + weight bf16 swizzle (proven r8-r17) ----------------
__global__ __launch_bounds__(256) void k_prep(const float* __restrict__ table,
    const float* __restrict__ Wkv, const float* __restrict__ Wq,
    const float* __restrict__ Wp,  const float* __restrict__ Wd,
    const float* __restrict__ W1,  const float* __restrict__ W2,
    float* __restrict__ bias, __bf16* __restrict__ wsw){
    int id = blockIdx.x * 256 + threadIdx.x;
    if (id < 196608){
        int k  = id & 63;
        int qg = (id >> 6) & 511;
        int h  = id >> 15;
        int qi = qg >> 6, qj = (qg >> 3) & 7, qk = qg & 7;
        int ki = k >> 4,  kj = (k >> 2) & 3,  kk = k & 3;
        int r0 = (qi >> 1) - ki + 3;
        int r1 = (qj >> 1) - kj + 3;
        int r2 = (qk >> 1) - kk + 3;
        bias[id] = table[((r0 * 7 + r1) * 7 + r2) * 6 + h];
        return;
    }
    id -= 196608;
    if (id >= NSWZ) return;
    if (id >= WD_OFF && id < W1_OFF){
        int lid  = id - WD_OFF;
        int j    = lid & 7, lane = (lid >> 3) & 63, tile = lid >> 9;
        int rt   = tile % 24;
        int kt2  = tile / 24;
        int ii   = kt2 / 6, kt = kt2 % 6;
        int n    = rt * 16 + (lane & 15);
        int o    = n % 96, jk = n / 96;
        int kdim = kt * 32 + (lane >> 4) * 8 + j;
        wsw[id] = (__bf16)(Wd[(kdim * 96 + o) * 8 + ii * 4 + jk]);
        return;
    }
    const float* W; int N, NRT, off; float sc = 1.f;
    if      (id < WQ_OFF){ W = Wkv; N = 384; NRT = 24; off = WKV_OFF; }
    else if (id < WP_OFF){ W = Wq;  N = 192; NRT = 12; off = WQ_OFF; sc = ATT_SCALE; }
    else if (id < WD_OFF){ W = Wp;  N = 96;  NRT = 6;  off = WP_OFF; }
    else if (id < W2_OFF){ W = W1;  N = 384; NRT = 24; off = W1_OFF; }
    else                 { W = W2;  N = 96;  NRT = 6;  off = W2_OFF; }
    int lid  = id - off;
    int j    = lid & 7, lane = (lid >> 3) & 63, tile = lid >> 9;
    int rt   = tile % NRT, kt = tile / NRT;
    int n    = rt * 16 + (lane & 15);
    int k    = kt * 32 + (lane >> 4) * 8 + j;
    wsw[id + 0] = (__bf16)(W[k * N + n] * sc);
}

// ---------------- fused windowed cross-attention (MFMA): attn + bpj (PURE STORE) ----------------
// 2 barriers/q-tile: P2 {scores+softmax+PV -> Os} | A {outproj(Os)->store ∥ qproj(qt+1)->Qs}
__global__ __launch_bounds__(512) void k_attn(const float* __restrict__ x,
    const float* __restrict__ xd, const float* __restrict__ g1, const float* __restrict__ b1v,
    const float* __restrict__ bkv, const float* __restrict__ bq, const float* __restrict__ bpj,
    const __bf16* __restrict__ wsw, const float* __restrict__ bias, float* __restrict__ yout,
    __bf16* __restrict__ aout){
    __shared__ __bf16 Qs[64][196];   // xln -> Q
    __shared__ __bf16 Os[64][196];   // attn-out (P2 output)
    __shared__ __bf16 Ks[64][196];
    __shared__ __bf16 Vt[192][68];   // V transposed [d][kv]
    __shared__ __bf16 Wq_s[18432];   // WQ staged (36 KB); WP stays global
    const int tid = threadIdx.x, lane = tid & 63, w = tid >> 6;
    const int win = blockIdx.x, b = win >> 8, wrem = win & 255;
    const int sw_ = wrem >> 6, hw_ = (wrem >> 3) & 7, ww_ = wrem & 7;

    // stage WQ into LDS; covered by the first barrier
    #pragma unroll
    for (int i = 0; i < 9; i++)
        ((uint2*)Wq_s)[tid + 512*i] = ((const uint2*)(wsw + WQ_OFF))[tid + 512*i];

    {   // LN stage of coarse x window -> Qs (as xln)
        int row = tid >> 3, sub = tid & 7;
        int si = row >> 4, hi = (row >> 2) & 3, wi = row & 3;
        int ci = ((b * 16 + 4 * sw_ + si) * 32 + 4 * hw_ + hi) * 32 + 4 * ww_ + wi;
        const float* xp = x + ci * 192 + sub * 24;
        float v[24]; float s = 0.f, ss = 0.f;
        #pragma unroll
        for (int i = 0; i < 6; i++){
            float4 t = ((const float4*)xp)[i];
            v[4*i] = t.x; v[4*i+1] = t.y; v[4*i+2] = t.z; v[4*i+3] = t.w;
            s += t.x + t.y + t.z + t.w;
            ss += t.x*t.x + t.y*t.y + t.z*t.z + t.w*t.w;
        }
        #pragma unroll
        for (int m = 1; m < 8; m <<= 1){ s += __shfl_xor(s, m); ss += __shfl_xor(ss, m); }
        float mu = s * (1.f/192.f), var = ss * (1.f/192.f) - mu*mu, rs = rsqrtf(var + 1e-5f);
        #pragma unroll
        for (int i = 0; i < 3; i++){
            bf16x8 t;
            #pragma unroll
            for (int jj = 0; jj < 8; jj++){
                int c = sub*24 + 8*i + jj;
                t[jj] = (__bf16)((v[8*i+jj] - mu) * rs * g1[c] + b1v[c]);
            }
            *(bf16x8*)&Qs[row][sub*24 + 8*i] = t;
        }
    }
    __syncthreads();
    {   // KVproj: KV^T = Wkv^T @ xln^T ; waves 0-3 -> K rows, 4-7 -> V^T
        const int ct = w & 3, rh = w >> 2;
        const int tok = ct * 16 + (lane & 15);
        bf16x8 bfr[6];
        #pragma unroll
        for (int kt = 0; kt < 6; kt++) bfr[kt] = *(const bf16x8*)&Qs[tok][kt*32 + (lane>>4)*8];
        #pragma unroll
        for (int i = 0; i < 12; i++){
            int rt = rh * 12 + i;
            f32x4 acc = {0.f,0.f,0.f,0.f};
            #pragma unroll
            for (int kt = 0; kt < 6; kt++) acc = MFMA16(afrag(wsw + WKV_OFF, 24, kt, rt, lane), bfr[kt], acc);
            int cb = rt * 16 + ((lane >> 4) << 2);
            float4 b4 = *(const float4*)&bkv[cb];
            acc[0] += b4.x; acc[1] += b4.y; acc[2] += b4.z; acc[3] += b4.w;
            if (cb < 192){
                bf16x4 t;
                #pragma unroll
                for (int r = 0; r < 4; r++) t[r] = (__bf16)acc[r];
                *(bf16x4*)&Ks[tok][cb] = t;
            } else {
                #pragma unroll
                for (int r = 0; r < 4; r++) Vt[cb - 192 + r][tok] = (__bf16)acc[r];
            }
        }
    }
    __syncthreads();

    const int li_ = lane & 15, gt_ = lane >> 4, rsel = lane >> 5;
    const int ctQ = w & 3, rhQ = w >> 2;
    const int qlQ = ctQ * 16 + li_;

    // qproj(qt): Q^T = Wq^T(scaled) @ xd^T -> Qs
    auto qproj = [&](int qt){
        const int ft = ((b * 32 + 8 * sw_ + qt) * 64 + 8 * hw_ + (qlQ >> 3)) * 64 + 8 * ww_ + (qlQ & 7);
        bf16x8 bfr[3];
        #pragma unroll
        for (int kt = 0; kt < 3; kt++){
            const float* xp = xd + ft * 96 + kt * 32 + gt_ * 8;
            float4 t0 = *(const float4*)xp;
            float4 t1 = *(const float4*)(xp + 4);
            bf16x8 t;
            t[0]=(__bf16)t0.x; t[1]=(__bf16)t0.y; t[2]=(__bf16)t0.z; t[3]=(__bf16)t0.w;
            t[4]=(__bf16)t1.x; t[5]=(__bf16)t1.y; t[6]=(__bf16)t1.z; t[7]=(__bf16)t1.w;
            bfr[kt] = t;
        }
        #pragma unroll
        for (int i = 0; i < 6; i++){
            int rt = rhQ * 6 + i;
            f32x4 acc = {0.f,0.f,0.f,0.f};
            #pragma unroll
            for (int kt = 0; kt < 3; kt++) acc = MFMA16(afrag(Wq_s, 12, kt, rt, lane), bfr[kt], acc);
            int cb = rt * 16 + (gt_ << 2);
            float4 b4 = *(const float4*)&bq[cb];
            bf16x4 t;
            t[0] = (__bf16)(acc[0] + b4.x * ATT_SCALE);
            t[1] = (__bf16)(acc[1] + b4.y * ATT_SCALE);
            t[2] = (__bf16)(acc[2] + b4.z * ATT_SCALE);
            t[3] = (__bf16)(acc[3] + b4.w * ATT_SCALE);
            *(bf16x4*)&Qs[qlQ][cb] = t;
        }
    };

    // outproj(qt): y = Wp^T @ Os^T + bpj  (pure store; WP from global)
    auto outproj = [&](int qt){
        const int ft = ((b * 32 + 8 * sw_ + qt) * 64 + 8 * hw_ + (qlQ >> 3)) * 64 + 8 * ww_ + (qlQ & 7);
        bf16x8 bfr[6];
        #pragma unroll
        for (int kt = 0; kt < 6; kt++) bfr[kt] = *(const bf16x8*)&Os[qlQ][kt*32 + gt_*8];
        #pragma unroll
        for (int i = 0; i < 3; i++){
            int rt = rhQ * 3 + i;
            f32x4 acc = {0.f,0.f,0.f,0.f};
            #pragma unroll
            for (int kt = 0; kt < 6; kt++) acc = MFMA16(afrag(wsw + WP_OFF, 6, kt, rt, lane), bfr[kt], acc);
            int cb = rt * 16 + (gt_ << 2);
            float4 b4 = *(const float4*)&bpj[cb];
            float4 res;
            res.x = acc[0] + b4.x;
            res.y = acc[1] + b4.y;
            res.z = acc[2] + b4.z;
            res.w = acc[3] + b4.w;
            if (aout){
                bf16x4 tb;
                tb[0] = (__bf16)res.x; tb[1] = (__bf16)res.y;
                tb[2] = (__bf16)res.z; tb[3] = (__bf16)res.w;
                *(bf16x4*)&aout[ft * 96 + cb] = tb;
            } else {
                *(float4*)&yout[ft * 96 + cb] = res;
            }
        }
    };

    qproj(0);
    __syncthreads();

    for (int qt = 0; qt < 8; qt++){
        // ---- P2: scores + softmax + in-register P redistribution + PV -> Os ----
        #pragma unroll
        for (int ui = 0; ui < 3; ui++){
            const int u = w * 3 + ui;
            const int h = u >> 2, qct = u & 3;
            f32x4 sc[4];
            __builtin_amdgcn_s_setprio(1);
            #pragma unroll
            for (int rt = 0; rt < 4; rt++){
                bf16x8 a  = *(const bf16x8*)&Ks[rt*16 + li_][h*32 + gt_*8];
                bf16x8 bq8 = *(const bf16x8*)&Qs[qct*16 + li_][h*32 + gt_*8];
                f32x4 z = {0.f,0.f,0.f,0.f};
                sc[rt] = MFMA16(a, bq8, z);
            }
            __builtin_amdgcn_s_setprio(0);
            const int qg = qt * 64 + qct * 16 + li_;
            const float* bp = bias + (h * 512 + qg) * 64 + (gt_ << 2);
            #pragma unroll
            for (int rt = 0; rt < 4; rt++){
                float4 b4 = *(const float4*)(bp + rt * 16);
                sc[rt][0] += b4.x; sc[rt][1] += b4.y; sc[rt][2] += b4.z; sc[rt][3] += b4.w;
            }
            float m = sc[0][0];
            #pragma unroll
            for (int rt = 0; rt < 4; rt++)
                #pragma unroll
                for (int r = 0; r < 4; r++) m = fmaxf(m, sc[rt][r]);
            m = fmaxf(m, __shfl_xor(m, 16));
            m = fmaxf(m, __shfl_xor(m, 32));
            float sum = 0.f;
            #pragma unroll
            for (int rt = 0; rt < 4; rt++)
                #pragma unroll
                for (int r = 0; r < 4; r++){ float e = __expf(sc[rt][r] - m); sc[rt][r] = e; sum += e; }
            sum += __shfl_xor(sum, 16);
            sum += __shfl_xor(sum, 32);
            float inv = 1.f / sum;
            unsigned pwv[4][2];
            #pragma unroll
            for (int rt = 0; rt < 4; rt++){
                union { __bf16 hh[2]; unsigned u; } c0, c1;
                c0.hh[0] = (__bf16)(sc[rt][0] * inv); c0.hh[1] = (__bf16)(sc[rt][1] * inv);
                c1.hh[0] = (__bf16)(sc[rt][2] * inv); c1.hh[1] = (__bf16)(sc[rt][3] * inv);
                pwv[rt][0] = c0.u; pwv[rt][1] = c1.u;
            }
            unsigned bfw[2][4];
            #pragma unroll
            for (int kt = 0; kt < 2; kt++){
                #pragma unroll
                for (int t = 0; t < 4; t++){
                    int gs   = ((gt_ & 1) << 1) + (t >> 1);
                    int addr = (((gs << 4) + li_) << 2);
                    int w0 = __builtin_amdgcn_ds_bpermute(addr, (int)pwv[2*kt + 0][t & 1]);
                    int w1 = __builtin_amdgcn_ds_bpermute(addr, (int)pwv[2*kt + 1][t & 1]);
                    bfw[kt][t] = rsel ? (unsigned)w1 : (unsigned)w0;
                }
            }
            union { unsigned u[4]; bf16x8 v; } pb0, pb1;
            #pragma unroll
            for (int t = 0; t < 4; t++){ pb0.u[t] = bfw[0][t]; pb1.u[t] = bfw[1][t]; }
            __builtin_amdgcn_s_setprio(1);
            #pragma unroll
            for (int dt = 0; dt < 2; dt++){
                f32x4 o = {0.f,0.f,0.f,0.f};
                bf16x8 a0 = *(const bf16x8*)&Vt[h*32 + dt*16 + li_][gt_*8];
                bf16x8 a1 = *(const bf16x8*)&Vt[h*32 + dt*16 + li_][32 + gt_*8];
                o = MFMA16(a0, pb0.v, o);
                o = MFMA16(a1, pb1.v, o);
                // write attn-out tile directly to Os (no Qs hazard)
                const int tok = qct * 16 + li_;
                int cb = h * 32 + dt * 16 + (gt_ << 2);
                bf16x4 t;
                #pragma unroll
                for (int r = 0; r < 4; r++) t[r] = (__bf16)o[r];
                *(bf16x4*)&Os[tok][cb] = t;
            }
            __builtin_amdgcn_s_setprio(0);
        }
        __syncthreads();
        // ---- phase A: outproj(qt) [pure store] + qproj(qt+1) ----
        outproj(qt);
        if (qt < 7) qproj(qt + 1);
        __syncthreads();
    }
}

// ---------------- MLP + fused deconv: 51.9 KB LDS -> 3 blocks/CU (r16-proven) ----------------
__global__ __launch_bounds__(512) void k_mlp(const float* __restrict__ x,
    const float* __restrict__ eg, const float* __restrict__ eb,
    const float* __restrict__ g2, const float* __restrict__ b2v,
    const __bf16* __restrict__ wsw, const float* __restrict__ db,
    const float* __restrict__ b1m, const float* __restrict__ b2m,
    float* __restrict__ outp, const __bf16* __restrict__ ain){
    __shared__ __bf16 xe[32][200];    // expand-LN of 32 coarse rows (12.8 KB)
    __shared__ __bf16 ybf[64][100];   // sc then y, bf16 (12.5 KB)
    __shared__ __bf16 yln[64][104];   // LN(y) (13.3 KB)
    __shared__ __bf16 hsm[64][104];   // gelu hidden chunk of 96 (13.3 KB)
    const int tid = threadIdx.x, lane = tid & 63, w = tid >> 6;
    const int t0 = blockIdx.x * 64;
    const int bb   = t0 >> 17;
    const int sbar = (t0 >> 12) & 31;
    const int hbar = (t0 >> 6) & 63;
    const int iD = sbar & 1, jD = hbar & 1;
    const int sc_ = sbar >> 1, hc_ = hbar >> 1;

    // T14 prefetch: this thread's attn values — consumed 2 phases later
    float4 apf[3];
    {
        int rowP = tid >> 3, subP = tid & 7;
        if (ain){
            const __bf16* ap = ain + (t0 + rowP) * 96 + subP * 12;
            #pragma unroll
            for (int i2 = 0; i2 < 3; i2++){
                bf16x4 a4 = ((const bf16x4*)ap)[i2];
                apf[i2].x = (float)a4[0]; apf[i2].y = (float)a4[1];
                apf[i2].z = (float)a4[2]; apf[i2].w = (float)a4[3];
            }
        } else {
            const float* ap = outp + (t0 + rowP) * 96 + subP * 12;
            apf[0] = ((const float4*)ap)[0];
            apf[1] = ((const float4*)ap)[1];
            apf[2] = ((const float4*)ap)[2];
        }
    }

    {   // stage 32 coarse x rows + expand-LN -> xe  (16 threads/row, 12 ch each)
        int row = tid >> 4, sub = tid & 15;
        int ci = ((bb * 16 + sc_) * 32 + hc_) * 32 + row;
        const float* xp = x + ci * 192 + sub * 12;
        float v[12]; float s = 0.f, ss = 0.f;
        #pragma unroll
        for (int i2 = 0; i2 < 3; i2++){
            float4 t = ((const float4*)xp)[i2];
            v[4*i2] = t.x; v[4*i2+1] = t.y; v[4*i2+2] = t.z; v[4*i2+3] = t.w;
            s += t.x + t.y + t.z + t.w;
            ss += t.x*t.x + t.y*t.y + t.z*t.z + t.w*t.w;
        }
        #pragma unroll
        for (int m = 1; m < 16; m <<= 1){ s += __shfl_xor(s, m); ss += __shfl_xor(ss, m); }
        float mu = s * (1.f/192.f), var = ss * (1.f/192.f) - mu*mu, rs = rsqrtf(var + 1e-5f);
        #pragma unroll
        for (int i2 = 0; i2 < 3; i2++){
            bf16x4 t;
            #pragma unroll
            for (int jj = 0; jj < 4; jj++){
                int c = sub*12 + 4*i2 + jj;
                t[jj] = (__bf16)((v[4*i2+jj] - mu) * rs * eg[c] + eb[c]);
            }
            *(bf16x4*)&xe[row][sub*12 + 4*i2] = t;
        }
    }
    __syncthreads();
    {   // deconv slice GEMM: C'[k*96+o][w] over K=192 -> ybf[2w+k][o] = sc + db (bf16)
        const int li = lane & 15, gt = lane >> 4;
        const int ctD = w & 1, rhD = w >> 1;
        const int wcol = ctD * 16 + li;
        bf16x8 bfrD[6];
        #pragma unroll
        for (int kt = 0; kt < 6; kt++) bfrD[kt] = *(const bf16x8*)&xe[wcol][kt*32 + gt*8];
        const __bf16* wd = wsw + WD_OFF + iD * 73728;
        #pragma unroll
        for (int i2 = 0; i2 < 3; i2++){
            int rtl = rhD * 3 + i2;               // [0,12)
            int rt  = 12 * jD + rtl;              // row tile in the ii=iD bank
            f32x4 acc = {0.f,0.f,0.f,0.f};
            #pragma unroll
            for (int kt = 0; kt < 6; kt++) acc = MFMA16(afrag(wd, 24, kt, rt, lane), bfrD[kt], acc);
            int mp   = rtl * 16 + (gt << 2);      // m' = k*96+o
            int kpar = (mp >= 96) ? 1 : 0;
            int o    = mp - 96 * kpar;
            int tok  = 2 * wcol + kpar;
            float4 d4 = *(const float4*)&db[o];
            bf16x4 t;
            t[0] = (__bf16)(acc[0] + d4.x); t[1] = (__bf16)(acc[1] + d4.y);
            t[2] = (__bf16)(acc[2] + d4.z); t[3] = (__bf16)(acc[3] + d4.w);
            *(bf16x4*)&ybf[tok][o] = t;
        }
    }
    __syncthreads();
    {   // y = attn(prefetched) + sc ; write y -> ybf (bf16) ; LN -> yln
        int row = tid >> 3, sub = tid & 7;
        float v[12]; float s = 0.f, ss = 0.f;
        #pragma unroll
        for (int i2 = 0; i2 < 3; i2++){
            float4 t = apf[i2];
            bf16x4 s4 = *(const bf16x4*)&ybf[row][sub*12 + 4*i2];
            t.x += (float)s4[0]; t.y += (float)s4[1];
            t.z += (float)s4[2]; t.w += (float)s4[3];
            v[4*i2] = t.x; v[4*i2+1] = t.y; v[4*i2+2] = t.z; v[4*i2+3] = t.w;
            s += t.x + t.y + t.z + t.w;
            ss += t.x*t.x + t.y*t.y + t.z*t.z + t.w*t.w;
            bf16x4 yb;
            yb[0] = (__bf16)t.x; yb[1] = (__bf16)t.y;
            yb[2] = (__bf16)t.z; yb[3] = (__bf16)t.w;
            *(bf16x4*)&ybf[row][sub*12 + 4*i2] = yb;   // y residual (bf16)
        }
        #pragma unroll
        for (int m = 1; m < 8; m <<= 1){ s += __shfl_xor(s, m); ss += __shfl_xor(ss, m); }
        float mu = s * (1.f/96.f), var = ss * (1.f/96.f) - mu*mu, rs = rsqrtf(var + 1e-5f);
        #pragma unroll
        for (int i2 = 0; i2 < 3; i2++){
            bf16x4 t;
            #pragma unroll
            for (int jj = 0; jj < 4; jj++){
                int c = sub*12 + 4*i2 + jj;
                t[jj] = (__bf16)((v[4*i2+jj] - mu) * rs * g2[c] + b2v[c]);
            }
            *(bf16x4*)&yln[row][sub*12 + 4*i2] = t;
        }
    }
    __syncthreads();
    const int ct = w & 3, rh = w >> 2;
    const int tok = ct * 16 + (lane & 15);
    bf16x8 bfrY[3];
    #pragma unroll
    for (int kt = 0; kt < 3; kt++) bfrY[kt] = *(const bf16x8*)&yln[tok][kt*32 + (lane>>4)*8];
    f32x4 oacc[3];
    #pragma unroll
    for (int i = 0; i < 3; i++){ f32x4 z = {0.f,0.f,0.f,0.f}; oacc[i] = z; }

    #pragma unroll
    for (int ch = 0; ch < 4; ch++){
        // GEMM1 chunk: 96 hidden channels -> hsm
        #pragma unroll
        for (int i = 0; i < 3; i++){
            int rtl = rh * 3 + i;            // [0,6)
            int rtg = ch * 6 + rtl;
            f32x4 acc = {0.f,0.f,0.f,0.f};
            #pragma unroll
            for (int kt = 0; kt < 3; kt++) acc = MFMA16(afrag(wsw + W1_OFF, 24, kt, rtg, lane), bfrY[kt], acc);
            int cb = rtl * 16 + ((lane >> 4) << 2);
            float4 b4 = *(const float4*)&b1m[ch * 96 + cb];
            bf16x4 t;
            t[0] = (__bf16)gelu_exact(acc[0] + b4.x);
            t[1] = (__bf16)gelu_exact(acc[1] + b4.y);
            t[2] = (__bf16)gelu_exact(acc[2] + b4.z);
            t[3] = (__bf16)gelu_exact(acc[3] + b4.w);
            *(bf16x4*)&hsm[tok][cb] = t;
        }
        __syncthreads();
        // GEMM2 chunk: accumulate o^T += W2chunk^T @ h^T
        bf16x8 bfrH[3];
        #pragma unroll
        for (int kt = 0; kt < 3; kt++) bfrH[kt] = *(const bf16x8*)&hsm[tok][kt*32 + (lane>>4)*8];
        #pragma unroll
        for (int i = 0; i < 3; i++){
            int rt = rh * 3 + i;
            #pragma unroll
            for (int kt = 0; kt < 3; kt++)
                oacc[i] = MFMA16(afrag(wsw + W2_OFF, 6, ch * 3 + kt, rt, lane), bfrH[kt], oacc[i]);
        }
        __syncthreads();
    }
    #pragma unroll
    for (int i = 0; i < 3; i++){
        int rt = rh * 3 + i;
        int cb = rt * 16 + ((lane >> 4) << 2);
        float4 b4 = *(const float4*)&b2m[cb];
        bf16x4 yv = *(const bf16x4*)&ybf[tok][cb];
        float4 res;
        res.x = (float)yv[0] + oacc[i][0] + b4.x;
        res.y = (float)yv[1] + oacc[i][1] + b4.y;
        res.z = (float)yv[2] + oacc[i][2] + b4.z;
        res.w = (float)yv[3] + oacc[i][3] + b4.w;
        *(float4*)&outp[(t0 + tok) * 96 + cb] = res;
    }
}

extern "C" void kernel_launch(void* const* d_in, const int* in_sizes, int n_in,
                              void* d_out, int out_size, void* d_ws, size_t ws_size,
                              hipStream_t stream){
    const float* x    = (const float*)d_in[0];
    const float* xd   = (const float*)d_in[1];
    const float* g1   = (const float*)d_in[2];
    const float* b1v  = (const float*)d_in[3];
    const float* Wkv  = (const float*)d_in[4];
    const float* bkv  = (const float*)d_in[5];
    const float* Wq   = (const float*)d_in[6];
    const float* bq   = (const float*)d_in[7];
    const float* Wp   = (const float*)d_in[8];
    const float* bpj  = (const float*)d_in[9];
    const float* btab = (const float*)d_in[10];
    const float* eg   = (const float*)d_in[11];
    const float* eb   = (const float*)d_in[12];
    const float* dw   = (const float*)d_in[13];
    const float* db   = (const float*)d_in[14];
    const float* g2   = (const float*)d_in[15];
    const float* b2v  = (const float*)d_in[16];
    const float* W1   = (const float*)d_in[17];
    const float* b1m  = (const float*)d_in[18];
    const float* W2   = (const float*)d_in[19];
    const float* b2m  = (const float*)d_in[20];
    (void)in_sizes; (void)n_in; (void)out_size;

    float*   out  = (float*)d_out;
    float*   bias = (float*)d_ws;
    __bf16*  wsw  = (__bf16*)((char*)d_ws + BIAS_BYTES);
    __bf16*  aout = (ws_size >= AOUT_OFF + AOUT_BYTES)
                    ? (__bf16*)((char*)d_ws + AOUT_OFF) : (__bf16*)nullptr;

    k_prep<<<2064, 256, 0, stream>>>(btab, Wkv, Wq, Wp, dw, W1, W2, bias, wsw);
    k_attn<<<512, 512, 0, stream>>>(x, xd, g1, b1v, bkv, bq, bpj, wsw, bias, out, aout);
    k_mlp <<<4096, 512, 0, stream>>>(x, eg, eb, g2, b2v, wsw, db, b1m, b2m, out, aout);
}

// Round 19
// 292.744 us; speedup vs baseline: 1.0110x; 1.0028x over previous
//
#include <hip/hip_runtime.h>
#include <math.h>

#define ATT_SCALE 0.17677669529663687f  // 32^-0.5

typedef __bf16 bf16x8 __attribute__((ext_vector_type(8)));
typedef __bf16 bf16x4 __attribute__((ext_vector_type(4)));
typedef float  f32x4  __attribute__((ext_vector_type(4)));

#define MFMA16(a,b,c) __builtin_amdgcn_mfma_f32_16x16x32_bf16(a,b,c,0,0,0)

// ws layout: [0,786432) f32 expanded bias; then bf16 swizzled weights; then optional bf16 attn-out
#define BIAS_BYTES 786432
#define WKV_OFF 0        // 192x384  kt6  NRT24
#define WQ_OFF  73728    // 96x192   kt3  NRT12 (pre-scaled)   [contiguous with WP]
#define WP_OFF  92160    // 192x96   kt6  NRT6
#define WD_OFF  110592   // deconv: [ii2][kt6][rt24][lane][8], rows m = (2j+k)*96+o
#define W1_OFF  258048   // 96x384   kt3  NRT24
#define W2_OFF  294912   // 384x96   kt12 NRT6
#define NSWZ    331776
#define AOUT_OFF 1507328ull                       // byte offset of bf16 attn-out in ws
#define AOUT_BYTES (262144ull * 96ull * 2ull)     // 50331648

static __device__ __forceinline__ float gelu_exact(float v){
    return 0.5f * v * (1.0f + erff(v * 0.70710678118654752f));
}

static __device__ __forceinline__ bf16x8 afrag(const __bf16* w, int NRT, int kt, int rt, int lane){
    return ((const bf16x8*)w)[(kt*NRT + rt)*64 + lane];
}

// ---------------- prep: bias expand + weight bf16 swizzle (proven r8-r18) ----------------
__global__ __launch_bounds__(256) void k_prep(const float* __restrict__ table,
    const float* __restrict__ Wkv, const float* __restrict__ Wq,
    const float* __restrict__ Wp,  const float* __restrict__ Wd,
    const float* __restrict__ W1,  const float* __restrict__ W2,
    float* __restrict__ bias, __bf16* __restrict__ wsw){
    int id = blockIdx.x * 256 + threadIdx.x;
    if (id < 196608){
        int k  = id & 63;
        int qg = (id >> 6) & 511;
        int h  = id >> 15;
        int qi = qg >> 6, qj = (qg >> 3) & 7, qk = qg & 7;
        int ki = k >> 4,  kj = (k >> 2) & 3,  kk = k & 3;
        int r0 = (qi >> 1) - ki + 3;
        int r1 = (qj >> 1) - kj + 3;
        int r2 = (qk >> 1) - kk + 3;
        bias[id] = table[((r0 * 7 + r1) * 7 + r2) * 6 + h];
        return;
    }
    id -= 196608;
    if (id >= NSWZ) return;
    if (id >= WD_OFF && id < W1_OFF){
        int lid  = id - WD_OFF;
        int j    = lid & 7, lane = (lid >> 3) & 63, tile = lid >> 9;
        int rt   = tile % 24;
        int kt2  = tile / 24;
        int ii   = kt2 / 6, kt = kt2 % 6;
        int n    = rt * 16 + (lane & 15);
        int o    = n % 96, jk = n / 96;
        int kdim = kt * 32 + (lane >> 4) * 8 + j;
        wsw[id] = (__bf16)(Wd[(kdim * 96 + o) * 8 + ii * 4 + jk]);
        return;
    }
    const float* W; int N, NRT, off; float sc = 1.f;
    if      (id < WQ_OFF){ W = Wkv; N = 384; NRT = 24; off = WKV_OFF; }
    else if (id < WP_OFF){ W = Wq;  N = 192; NRT = 12; off = WQ_OFF; sc = ATT_SCALE; }
    else if (id < WD_OFF){ W = Wp;  N = 96;  NRT = 6;  off = WP_OFF; }
    else if (id < W2_OFF){ W = W1;  N = 384; NRT = 24; off = W1_OFF; }
    else                 { W = W2;  N = 96;  NRT = 6;  off = W2_OFF; }
    int lid  = id - off;
    int j    = lid & 7, lane = (lid >> 3) & 63, tile = lid >> 9;
    int rt   = tile % NRT, kt = tile / NRT;
    int n    = rt * 16 + (lane & 15);
    int k    = kt * 32 + (lane >> 4) * 8 + j;
    wsw[id + 0] = (__bf16)(W[k * N + n] * sc);
}

// ---------------- fused windowed cross-attention (MFMA): attn + bpj (PURE STORE) ----------------
// 2 barriers/q-tile; phase A issues qproj(qt+1) xd loads BEFORE outproj (same-phase, no cross-barrier state)
__global__ __launch_bounds__(512) void k_attn(const float* __restrict__ x,
    const float* __restrict__ xd, const float* __restrict__ g1, const float* __restrict__ b1v,
    const float* __restrict__ bkv, const float* __restrict__ bq, const float* __restrict__ bpj,
    const __bf16* __restrict__ wsw, const float* __restrict__ bias, float* __restrict__ yout,
    __bf16* __restrict__ aout){
    __shared__ __bf16 Qs[64][196];   // xln -> Q
    __shared__ __bf16 Os[64][196];   // attn-out (P2 output)
    __shared__ __bf16 Ks[64][196];
    __shared__ __bf16 Vt[192][68];   // V transposed [d][kv]
    __shared__ __bf16 Wq_s[18432];   // WQ staged (36 KB); WP stays global
    const int tid = threadIdx.x, lane = tid & 63, w = tid >> 6;
    const int win = blockIdx.x, b = win >> 8, wrem = win & 255;
    const int sw_ = wrem >> 6, hw_ = (wrem >> 3) & 7, ww_ = wrem & 7;

    // stage WQ into LDS; covered by the first barrier
    #pragma unroll
    for (int i = 0; i < 9; i++)
        ((uint2*)Wq_s)[tid + 512*i] = ((const uint2*)(wsw + WQ_OFF))[tid + 512*i];

    {   // LN stage of coarse x window -> Qs (as xln)
        int row = tid >> 3, sub = tid & 7;
        int si = row >> 4, hi = (row >> 2) & 3, wi = row & 3;
        int ci = ((b * 16 + 4 * sw_ + si) * 32 + 4 * hw_ + hi) * 32 + 4 * ww_ + wi;
        const float* xp = x + ci * 192 + sub * 24;
        float v[24]; float s = 0.f, ss = 0.f;
        #pragma unroll
        for (int i = 0; i < 6; i++){
            float4 t = ((const float4*)xp)[i];
            v[4*i] = t.x; v[4*i+1] = t.y; v[4*i+2] = t.z; v[4*i+3] = t.w;
            s += t.x + t.y + t.z + t.w;
            ss += t.x*t.x + t.y*t.y + t.z*t.z + t.w*t.w;
        }
        #pragma unroll
        for (int m = 1; m < 8; m <<= 1){ s += __shfl_xor(s, m); ss += __shfl_xor(ss, m); }
        float mu = s * (1.f/192.f), var = ss * (1.f/192.f) - mu*mu, rs = rsqrtf(var + 1e-5f);
        #pragma unroll
        for (int i = 0; i < 3; i++){
            bf16x8 t;
            #pragma unroll
            for (int jj = 0; jj < 8; jj++){
                int c = sub*24 + 8*i + jj;
                t[jj] = (__bf16)((v[8*i+jj] - mu) * rs * g1[c] + b1v[c]);
            }
            *(bf16x8*)&Qs[row][sub*24 + 8*i] = t;
        }
    }
    __syncthreads();
    {   // KVproj: KV^T = Wkv^T @ xln^T ; waves 0-3 -> K rows, 4-7 -> V^T
        const int ct = w & 3, rh = w >> 2;
        const int tok = ct * 16 + (lane & 15);
        bf16x8 bfr[6];
        #pragma unroll
        for (int kt = 0; kt < 6; kt++) bfr[kt] = *(const bf16x8*)&Qs[tok][kt*32 + (lane>>4)*8];
        #pragma unroll
        for (int i = 0; i < 12; i++){
            int rt = rh * 12 + i;
            f32x4 acc = {0.f,0.f,0.f,0.f};
            #pragma unroll
            for (int kt = 0; kt < 6; kt++) acc = MFMA16(afrag(wsw + WKV_OFF, 24, kt, rt, lane), bfr[kt], acc);
            int cb = rt * 16 + ((lane >> 4) << 2);
            float4 b4 = *(const float4*)&bkv[cb];
            acc[0] += b4.x; acc[1] += b4.y; acc[2] += b4.z; acc[3] += b4.w;
            if (cb < 192){
                bf16x4 t;
                #pragma unroll
                for (int r = 0; r < 4; r++) t[r] = (__bf16)acc[r];
                *(bf16x4*)&Ks[tok][cb] = t;
            } else {
                #pragma unroll
                for (int r = 0; r < 4; r++) Vt[cb - 192 + r][tok] = (__bf16)acc[r];
            }
        }
    }
    __syncthreads();

    const int li_ = lane & 15, gt_ = lane >> 4, rsel = lane >> 5;
    const int ctQ = w & 3, rhQ = w >> 2;
    const int qlQ = ctQ * 16 + li_;

    // qproj MFMA part: consume preloaded xd rows -> Qs
    auto qproj_mfma = [&](const float4* pf){
        bf16x8 bfr[3];
        #pragma unroll
        for (int kt = 0; kt < 3; kt++){
            float4 t0 = pf[2*kt + 0];
            float4 t1 = pf[2*kt + 1];
            bf16x8 t;
            t[0]=(__bf16)t0.x; t[1]=(__bf16)t0.y; t[2]=(__bf16)t0.z; t[3]=(__bf16)t0.w;
            t[4]=(__bf16)t1.x; t[5]=(__bf16)t1.y; t[6]=(__bf16)t1.z; t[7]=(__bf16)t1.w;
            bfr[kt] = t;
        }
        #pragma unroll
        for (int i = 0; i < 6; i++){
            int rt = rhQ * 6 + i;
            f32x4 acc = {0.f,0.f,0.f,0.f};
            #pragma unroll
            for (int kt = 0; kt < 3; kt++) acc = MFMA16(afrag(Wq_s, 12, kt, rt, lane), bfr[kt], acc);
            int cb = rt * 16 + (gt_ << 2);
            float4 b4 = *(const float4*)&bq[cb];
            bf16x4 t;
            t[0] = (__bf16)(acc[0] + b4.x * ATT_SCALE);
            t[1] = (__bf16)(acc[1] + b4.y * ATT_SCALE);
            t[2] = (__bf16)(acc[2] + b4.z * ATT_SCALE);
            t[3] = (__bf16)(acc[3] + b4.w * ATT_SCALE);
            *(bf16x4*)&Qs[qlQ][cb] = t;
        }
    };
    auto qload = [&](int qt, float4* pf){
        const int ft = ((b * 32 + 8 * sw_ + qt) * 64 + 8 * hw_ + (qlQ >> 3)) * 64 + 8 * ww_ + (qlQ & 7);
        #pragma unroll
        for (int kt = 0; kt < 3; kt++){
            const float* xp = xd + ft * 96 + kt * 32 + gt_ * 8;
            pf[2*kt + 0] = *(const float4*)xp;
            pf[2*kt + 1] = *(const float4*)(xp + 4);
        }
    };

    // outproj(qt): y = Wp^T @ Os^T + bpj  (pure store; WP from global)
    auto outproj = [&](int qt){
        const int ft = ((b * 32 + 8 * sw_ + qt) * 64 + 8 * hw_ + (qlQ >> 3)) * 64 + 8 * ww_ + (qlQ & 7);
        bf16x8 bfr[6];
        #pragma unroll
        for (int kt = 0; kt < 6; kt++) bfr[kt] = *(const bf16x8*)&Os[qlQ][kt*32 + gt_*8];
        #pragma unroll
        for (int i = 0; i < 3; i++){
            int rt = rhQ * 3 + i;
            f32x4 acc = {0.f,0.f,0.f,0.f};
            #pragma unroll
            for (int kt = 0; kt < 6; kt++) acc = MFMA16(afrag(wsw + WP_OFF, 6, kt, rt, lane), bfr[kt], acc);
            int cb = rt * 16 + (gt_ << 2);
            float4 b4 = *(const float4*)&bpj[cb];
            float4 res;
            res.x = acc[0] + b4.x;
            res.y = acc[1] + b4.y;
            res.z = acc[2] + b4.z;
            res.w = acc[3] + b4.w;
            if (aout){
                bf16x4 tb;
                tb[0] = (__bf16)res.x; tb[1] = (__bf16)res.y;
                tb[2] = (__bf16)res.z; tb[3] = (__bf16)res.w;
                *(bf16x4*)&aout[ft * 96 + cb] = tb;
            } else {
                *(float4*)&yout[ft * 96 + cb] = res;
            }
        }
    };

    {
        float4 pf0[6];
        qload(0, pf0);
        qproj_mfma(pf0);
    }
    __syncthreads();

    for (int qt = 0; qt < 8; qt++){
        // ---- P2: scores + softmax + in-register P redistribution + PV -> Os ----
        #pragma unroll
        for (int ui = 0; ui < 3; ui++){
            const int u = w * 3 + ui;
            const int h = u >> 2, qct = u & 3;
            f32x4 sc[4];
            __builtin_amdgcn_s_setprio(1);
            #pragma unroll
            for (int rt = 0; rt < 4; rt++){
                bf16x8 a  = *(const bf16x8*)&Ks[rt*16 + li_][h*32 + gt_*8];
                bf16x8 bq8 = *(const bf16x8*)&Qs[qct*16 + li_][h*32 + gt_*8];
                f32x4 z = {0.f,0.f,0.f,0.f};
                sc[rt] = MFMA16(a, bq8, z);
            }
            __builtin_amdgcn_s_setprio(0);
            const int qg = qt * 64 + qct * 16 + li_;
            const float* bp = bias + (h * 512 + qg) * 64 + (gt_ << 2);
            #pragma unroll
            for (int rt = 0; rt < 4; rt++){
                float4 b4 = *(const float4*)(bp + rt * 16);
                sc[rt][0] += b4.x; sc[rt][1] += b4.y; sc[rt][2] += b4.z; sc[rt][3] += b4.w;
            }
            float m = sc[0][0];
            #pragma unroll
            for (int rt = 0; rt < 4; rt++)
                #pragma unroll
                for (int r = 0; r < 4; r++) m = fmaxf(m, sc[rt][r]);
            m = fmaxf(m, __shfl_xor(m, 16));
            m = fmaxf(m, __shfl_xor(m, 32));
            float sum = 0.f;
            #pragma unroll
            for (int rt = 0; rt < 4; rt++)
                #pragma unroll
                for (int r = 0; r < 4; r++){ float e = __expf(sc[rt][r] - m); sc[rt][r] = e; sum += e; }
            sum += __shfl_xor(sum, 16);
            sum += __shfl_xor(sum, 32);
            float inv = 1.f / sum;
            unsigned pwv[4][2];
            #pragma unroll
            for (int rt = 0; rt < 4; rt++){
                union { __bf16 hh[2]; unsigned u; } c0, c1;
                c0.hh[0] = (__bf16)(sc[rt][0] * inv); c0.hh[1] = (__bf16)(sc[rt][1] * inv);
                c1.hh[0] = (__bf16)(sc[rt][2] * inv); c1.hh[1] = (__bf16)(sc[rt][3] * inv);
                pwv[rt][0] = c0.u; pwv[rt][1] = c1.u;
            }
            unsigned bfw[2][4];
            #pragma unroll
            for (int kt = 0; kt < 2; kt++){
                #pragma unroll
                for (int t = 0; t < 4; t++){
                    int gs   = ((gt_ & 1) << 1) + (t >> 1);
                    int addr = (((gs << 4) + li_) << 2);
                    int w0 = __builtin_amdgcn_ds_bpermute(addr, (int)pwv[2*kt + 0][t & 1]);
                    int w1 = __builtin_amdgcn_ds_bpermute(addr, (int)pwv[2*kt + 1][t & 1]);
                    bfw[kt][t] = rsel ? (unsigned)w1 : (unsigned)w0;
                }
            }
            union { unsigned u[4]; bf16x8 v; } pb0, pb1;
            #pragma unroll
            for (int t = 0; t < 4; t++){ pb0.u[t] = bfw[0][t]; pb1.u[t] = bfw[1][t]; }
            __builtin_amdgcn_s_setprio(1);
            #pragma unroll
            for (int dt = 0; dt < 2; dt++){
                f32x4 o = {0.f,0.f,0.f,0.f};
                bf16x8 a0 = *(const bf16x8*)&Vt[h*32 + dt*16 + li_][gt_*8];
                bf16x8 a1 = *(const bf16x8*)&Vt[h*32 + dt*16 + li_][32 + gt_*8];
                o = MFMA16(a0, pb0.v, o);
                o = MFMA16(a1, pb1.v, o);
                const int tok = qct * 16 + li_;
                int cb = h * 32 + dt * 16 + (gt_ << 2);
                bf16x4 t;
                #pragma unroll
                for (int r = 0; r < 4; r++) t[r] = (__bf16)o[r];
                *(bf16x4*)&Os[tok][cb] = t;
            }
            __builtin_amdgcn_s_setprio(0);
        }
        __syncthreads();
        // ---- phase A: issue xd loads(qt+1) FIRST, outproj(qt), then qproj MFMA ----
        {
            float4 pf[6];
            if (qt < 7) qload(qt + 1, pf);
            outproj(qt);
            if (qt < 7) qproj_mfma(pf);
        }
        __syncthreads();
    }
}

// ---------------- MLP + fused deconv: 51.9 KB LDS -> 3 blocks/CU (r16/r18-proven) ----------------
__global__ __launch_bounds__(512) void k_mlp(const float* __restrict__ x,
    const float* __restrict__ eg, const float* __restrict__ eb,
    const float* __restrict__ g2, const float* __restrict__ b2v,
    const __bf16* __restrict__ wsw, const float* __restrict__ db,
    const float* __restrict__ b1m, const float* __restrict__ b2m,
    float* __restrict__ outp, const __bf16* __restrict__ ain){
    __shared__ __bf16 xe[32][200];    // expand-LN of 32 coarse rows (12.8 KB)
    __shared__ __bf16 ybf[64][100];   // sc then y, bf16 (12.5 KB)
    __shared__ __bf16 yln[64][104];   // LN(y) (13.3 KB)
    __shared__ __bf16 hsm[64][104];   // gelu hidden chunk of 96 (13.3 KB)
    const int tid = threadIdx.x, lane = tid & 63, w = tid >> 6;
    const int t0 = blockIdx.x * 64;
    const int bb   = t0 >> 17;
    const int sbar = (t0 >> 12) & 31;
    const int hbar = (t0 >> 6) & 63;
    const int iD = sbar & 1, jD = hbar & 1;
    const int sc_ = sbar >> 1, hc_ = hbar >> 1;

    // T14 prefetch: this thread's attn values — consumed 2 phases later
    float4 apf[3];
    {
        int rowP = tid >> 3, subP = tid & 7;
        if (ain){
            const __bf16* ap = ain + (t0 + rowP) * 96 + subP * 12;
            #pragma unroll
            for (int i2 = 0; i2 < 3; i2++){
                bf16x4 a4 = ((const bf16x4*)ap)[i2];
                apf[i2].x = (float)a4[0]; apf[i2].y = (float)a4[1];
                apf[i2].z = (float)a4[2]; apf[i2].w = (float)a4[3];
            }
        } else {
            const float* ap = outp + (t0 + rowP) * 96 + subP * 12;
            apf[0] = ((const float4*)ap)[0];
            apf[1] = ((const float4*)ap)[1];
            apf[2] = ((const float4*)ap)[2];
        }
    }

    {   // stage 32 coarse x rows + expand-LN -> xe  (16 threads/row, 12 ch each)
        int row = tid >> 4, sub = tid & 15;
        int ci = ((bb * 16 + sc_) * 32 + hc_) * 32 + row;
        const float* xp = x + ci * 192 + sub * 12;
        float v[12]; float s = 0.f, ss = 0.f;
        #pragma unroll
        for (int i2 = 0; i2 < 3; i2++){
            float4 t = ((const float4*)xp)[i2];
            v[4*i2] = t.x; v[4*i2+1] = t.y; v[4*i2+2] = t.z; v[4*i2+3] = t.w;
            s += t.x + t.y + t.z + t.w;
            ss += t.x*t.x + t.y*t.y + t.z*t.z + t.w*t.w;
        }
        #pragma unroll
        for (int m = 1; m < 16; m <<= 1){ s += __shfl_xor(s, m); ss += __shfl_xor(ss, m); }
        float mu = s * (1.f/192.f), var = ss * (1.f/192.f) - mu*mu, rs = rsqrtf(var + 1e-5f);
        #pragma unroll
        for (int i2 = 0; i2 < 3; i2++){
            bf16x4 t;
            #pragma unroll
            for (int jj = 0; jj < 4; jj++){
                int c = sub*12 + 4*i2 + jj;
                t[jj] = (__bf16)((v[4*i2+jj] - mu) * rs * eg[c] + eb[c]);
            }
            *(bf16x4*)&xe[row][sub*12 + 4*i2] = t;
        }
    }
    __syncthreads();
    {   // deconv slice GEMM: C'[k*96+o][w] over K=192 -> ybf[2w+k][o] = sc + db (bf16)
        const int li = lane & 15, gt = lane >> 4;
        const int ctD = w & 1, rhD = w >> 1;
        const int wcol = ctD * 16 + li;
        bf16x8 bfrD[6];
        #pragma unroll
        for (int kt = 0; kt < 6; kt++) bfrD[kt] = *(const bf16x8*)&xe[wcol][kt*32 + gt*8];
        const __bf16* wd = wsw + WD_OFF + iD * 73728;
        #pragma unroll
        for (int i2 = 0; i2 < 3; i2++){
            int rtl = rhD * 3 + i2;               // [0,12)
            int rt  = 12 * jD + rtl;              // row tile in the ii=iD bank
            f32x4 acc = {0.f,0.f,0.f,0.f};
            #pragma unroll
            for (int kt = 0; kt < 6; kt++) acc = MFMA16(afrag(wd, 24, kt, rt, lane), bfrD[kt], acc);
            int mp   = rtl * 16 + (gt << 2);      // m' = k*96+o
            int kpar = (mp >= 96) ? 1 : 0;
            int o    = mp - 96 * kpar;
            int tok  = 2 * wcol + kpar;
            float4 d4 = *(const float4*)&db[o];
            bf16x4 t;
            t[0] = (__bf16)(acc[0] + d4.x); t[1] = (__bf16)(acc[1] + d4.y);
            t[2] = (__bf16)(acc[2] + d4.z); t[3] = (__bf16)(acc[3] + d4.w);
            *(bf16x4*)&ybf[tok][o] = t;
        }
    }
    __syncthreads();
    {   // y = attn(prefetched) + sc ; write y -> ybf (bf16) ; LN -> yln
        int row = tid >> 3, sub = tid & 7;
        float v[12]; float s = 0.f, ss = 0.f;
        #pragma unroll
        for (int i2 = 0; i2 < 3; i2++){
            float4 t = apf[i2];
            bf16x4 s4 = *(const bf16x4*)&ybf[row][sub*12 + 4*i2];
            t.x += (float)s4[0]; t.y += (float)s4[1];
            t.z += (float)s4[2]; t.w += (float)s4[3];
            v[4*i2] = t.x; v[4*i2+1] = t.y; v[4*i2+2] = t.z; v[4*i2+3] = t.w;
            s += t.x + t.y + t.z + t.w;
            ss += t.x*t.x + t.y*t.y + t.z*t.z + t.w*t.w;
            bf16x4 yb;
            yb[0] = (__bf16)t.x; yb[1] = (__bf16)t.y;
            yb[2] = (__bf16)t.z; yb[3] = (__bf16)t.w;
            *(bf16x4*)&ybf[row][sub*12 + 4*i2] = yb;   // y residual (bf16)
        }
        #pragma unroll
        for (int m = 1; m < 8; m <<= 1){ s += __shfl_xor(s, m); ss += __shfl_xor(ss, m); }
        float mu = s * (1.f/96.f), var = ss * (1.f/96.f) - mu*mu, rs = rsqrtf(var + 1e-5f);
        #pragma unroll
        for (int i2 = 0; i2 < 3; i2++){
            bf16x4 t;
            #pragma unroll
            for (int jj = 0; jj < 4; jj++){
                int c = sub*12 + 4*i2 + jj;
                t[jj] = (__bf16)((v[4*i2+jj] - mu) * rs * g2[c] + b2v[c]);
            }
            *(bf16x4*)&yln[row][sub*12 + 4*i2] = t;
        }
    }
    __syncthreads();
    const int ct = w & 3, rh = w >> 2;
    const int tok = ct * 16 + (lane & 15);
    bf16x8 bfrY[3];
    #pragma unroll
    for (int kt = 0; kt < 3; kt++) bfrY[kt] = *(const bf16x8*)&yln[tok][kt*32 + (lane>>4)*8];
    f32x4 oacc[3];
    #pragma unroll
    for (int i = 0; i < 3; i++){ f32x4 z = {0.f,0.f,0.f,0.f}; oacc[i] = z; }

    #pragma unroll
    for (int ch = 0; ch < 4; ch++){
        // GEMM1 chunk: 96 hidden channels -> hsm
        #pragma unroll
        for (int i = 0; i < 3; i++){
            int rtl = rh * 3 + i;            // [0,6)
            int rtg = ch * 6 + rtl;
            f32x4 acc = {0.f,0.f,0.f,0.f};
            #pragma unroll
            for (int kt = 0; kt < 3; kt++) acc = MFMA16(afrag(wsw + W1_OFF, 24, kt, rtg, lane), bfrY[kt], acc);
            int cb = rtl * 16 + ((lane >> 4) << 2);
            float4 b4 = *(const float4*)&b1m[ch * 96 + cb];
            bf16x4 t;
            t[0] = (__bf16)gelu_exact(acc[0] + b4.x);
            t[1] = (__bf16)gelu_exact(acc[1] + b4.y);
            t[2] = (__bf16)gelu_exact(acc[2] + b4.z);
            t[3] = (__bf16)gelu_exact(acc[3] + b4.w);
            *(bf16x4*)&hsm[tok][cb] = t;
        }
        __syncthreads();
        // GEMM2 chunk: accumulate o^T += W2chunk^T @ h^T
        bf16x8 bfrH[3];
        #pragma unroll
        for (int kt = 0; kt < 3; kt++) bfrH[kt] = *(const bf16x8*)&hsm[tok][kt*32 + (lane>>4)*8];
        #pragma unroll
        for (int i = 0; i < 3; i++){
            int rt = rh * 3 + i;
            #pragma unroll
            for (int kt = 0; kt < 3; kt++)
                oacc[i] = MFMA16(afrag(wsw + W2_OFF, 6, ch * 3 + kt, rt, lane), bfrH[kt], oacc[i]);
        }
        __syncthreads();
    }
    #pragma unroll
    for (int i = 0; i < 3; i++){
        int rt = rh * 3 + i;
        int cb = rt * 16 + ((lane >> 4) << 2);
        float4 b4 = *(const float4*)&b2m[cb];
        bf16x4 yv = *(const bf16x4*)&ybf[tok][cb];
        float4 res;
        res.x = (float)yv[0] + oacc[i][0] + b4.x;
        res.y = (float)yv[1] + oacc[i][1] + b4.y;
        res.z = (float)yv[2] + oacc[i][2] + b4.z;
        res.w = (float)yv[3] + oacc[i][3] + b4.w;
        *(float4*)&outp[(t0 + tok) * 96 + cb] = res;
    }
}

extern "C" void kernel_launch(void* const* d_in, const int* in_sizes, int n_in,
                              void* d_out, int out_size, void* d_ws, size_t ws_size,
                              hipStream_t stream){
    const float* x    = (const float*)d_in[0];
    const float* xd   = (const float*)d_in[1];
    const float* g1   = (const float*)d_in[2];
    const float* b1v  = (const float*)d_in[3];
    const float* Wkv  = (const float*)d_in[4];
    const float* bkv  = (const float*)d_in[5];
    const float* Wq   = (const float*)d_in[6];
    const float* bq   = (const float*)d_in[7];
    const float* Wp   = (const float*)d_in[8];
    const float* bpj  = (const float*)d_in[9];
    const float* btab = (const float*)d_in[10];
    const float* eg   = (const float*)d_in[11];
    const float* eb   = (const float*)d_in[12];
    const float* dw   = (const float*)d_in[13];
    const float* db   = (const float*)d_in[14];
    const float* g2   = (const float*)d_in[15];
    const float* b2v  = (const float*)d_in[16];
    const float* W1   = (const float*)d_in[17];
    const float* b1m  = (const float*)d_in[18];
    const float* W2   = (const float*)d_in[19];
    const float* b2m  = (const float*)d_in[20];
    (void)in_sizes; (void)n_in; (void)out_size;

    float*   out  = (float*)d_out;
    float*   bias = (float*)d_ws;
    __bf16*  wsw  = (__bf16*)((char*)d_ws + BIAS_BYTES);
    __bf16*  aout = (ws_size >= AOUT_OFF + AOUT_BYTES)
                    ? (__bf16*)((char*)d_ws + AOUT_OFF) : (__bf16*)nullptr;

    k_prep<<<2064, 256, 0, stream>>>(btab, Wkv, Wq, Wp, dw, W1, W2, bias, wsw);
    k_attn<<<512, 512, 0, stream>>>(x, xd, g1, b1v, bkv, bq, bpj, wsw, bias, out, aout);
    k_mlp <<<4096, 512, 0, stream>>>(x, eg, eb, g2, b2v, wsw, db, b1m, b2m, out, aout);
}